// Round 5
// baseline (2227.019 us; speedup 1.0000x reference)
//
#include <hip/hip_runtime.h>
#include <hip/hip_bf16.h>
#include <math.h>

#define BB 8
#define SS 512
#define DD 1024
#define LL 6
#define HH 8
#define HDD 128
#define FFF 4096
#define EPSF 1e-5f
#define SCALEF 0.08838834764831845f  // 1/sqrt(128)

typedef __attribute__((ext_vector_type(8))) _Float16 f16x8;
typedef __attribute__((ext_vector_type(4))) _Float16 f16x4;
typedef __attribute__((ext_vector_type(4))) float f32x4;

__device__ __forceinline__ void gload16(const void* g, void* l) {
  __builtin_amdgcn_global_load_lds(
      (const __attribute__((address_space(1))) void*)g,
      (__attribute__((address_space(3))) void*)l, 16, 0, 0);
}

// ===========================================================================
// gemm3: 256x256 tile, 512 threads (8 waves, 2M x 4N), wave-tile 128x64,
// BK=32, 16x16x32 MFMA, triple-buffered counted-vmcnt pipeline:
//   step t: { s_waitcnt vmcnt(4); s_barrier; STAGE(t+2); COMPUTE(t) }
// LDS 3 x 32KB (A 16KB + B 16KB per buffer). Swizzle: 16B slot ^= (row>>1)&3
// applied to global SOURCE of global_load_lds and to ds_read (both-sides).
// A [M,K] f16 rows stride Kstr; B [N,K] f16 rows stride Kstr; K-loop = Kdim.
// emode: 1 fused-qkv scatter (N=3072, V transposed) | 2 scores(scale+mask) |
//        5 gelu+bias f16 | 6 f16 partial (split-K, no bias)
// ===========================================================================
#define BUF3 32768

#define STAGE3(P, KB)                         \
  {                                           \
    gload16(A0 + (KB), lb + (P) + tid * 16);  \
    gload16(A1 + (KB), lb + (P) + 8192 + tid * 16);  \
    gload16(B0 + (KB), lb + (P) + 16384 + tid * 16); \
    gload16(B1 + (KB), lb + (P) + 24576 + tid * 16); \
  }

#define COMP3(P)                                                           \
  {                                                                        \
    f16x8 af[8], bf[4];                                                    \
    _Pragma("unroll") for (int mi = 0; mi < 8; ++mi)                       \
        af[mi] = *(const f16x8*)(lb + (P) + adA[mi]);                      \
    _Pragma("unroll") for (int ni = 0; ni < 4; ++ni)                       \
        bf[ni] = *(const f16x8*)(lb + (P) + 16384 + adB[ni]);              \
    _Pragma("unroll") for (int mi = 0; mi < 8; ++mi)                       \
        _Pragma("unroll") for (int ni = 0; ni < 4; ++ni)                   \
            acc[mi][ni] = __builtin_amdgcn_mfma_f32_16x16x32_f16(          \
                af[mi], bf[ni], acc[mi][ni], 0, 0, 0);                     \
  }

#define WB3_4                                         \
  {                                                   \
    asm volatile("s_waitcnt vmcnt(4)" ::: "memory");  \
    __builtin_amdgcn_s_barrier();                     \
  }
#define WB3_0                                         \
  {                                                   \
    asm volatile("s_waitcnt vmcnt(0)" ::: "memory");  \
    __builtin_amdgcn_s_barrier();                     \
  }

__global__ __launch_bounds__(512, 2) void gemm3_kernel(
    const _Float16* __restrict__ Ag, const _Float16* __restrict__ Bg,
    const float* __restrict__ bias, void* __restrict__ outp,
    const int* __restrict__ amask, int Mdim, int Ndim, int Kdim, int Kstr,
    long zsA, long zsB, long zsOut, int emode) {
  __shared__ char lb[3 * BUF3];  // 96KB
  const int tid = threadIdx.x;
  const int lane = tid & 63;
  const int wid = tid >> 6;
  const int z = blockIdx.z;
  const int m0 = blockIdx.y * 256;
  const int n0 = blockIdx.x * 256;
  const _Float16* Az = Ag + (long)z * zsA + (long)m0 * Kstr;
  const _Float16* Bz = Bg + (long)z * zsB + (long)n0 * Kstr;

  const int wm = (wid >> 2) * 128;  // wave-tile 128x64
  const int wn = (wid & 3) * 64;
  const int r16 = lane & 15;
  const int kq = lane >> 4;  // 16B slot index 0..3

  // staging source pointers (swizzled 16B slot within each 64B row-chunk)
  const int r0 = tid >> 2;                     // 0..127
  const int slot = tid & 3;
  const int sw = (r0 >> 1) & 3;
  const int cb = ((slot ^ sw) << 4);           // source byte within row-chunk
  const char* A0 = (const char*)Az + (long)r0 * Kstr * 2 + cb;
  const char* A1 = A0 + (long)128 * Kstr * 2;
  const char* B0 = (const char*)Bz + (long)r0 * Kstr * 2 + cb;
  const char* B1 = B0 + (long)128 * Kstr * 2;

  // ds_read addresses (constant over steps; BK=32 -> single k-chunk)
  int adA[8], adB[4];
#pragma unroll
  for (int mi = 0; mi < 8; ++mi) {
    const int R = wm + mi * 16 + r16;
    adA[mi] = R * 64 + ((kq ^ ((R >> 1) & 3)) << 4);
  }
#pragma unroll
  for (int ni = 0; ni < 4; ++ni) {
    const int R = wn + ni * 16 + r16;
    adB[ni] = R * 64 + ((kq ^ ((R >> 1) & 3)) << 4);
  }

  f32x4 acc[8][4];
#pragma unroll
  for (int mi = 0; mi < 8; ++mi)
#pragma unroll
    for (int ni = 0; ni < 4; ++ni) acc[mi][ni] = (f32x4){0.f, 0.f, 0.f, 0.f};

  const int nt = Kdim >> 5;  // BK=32 -> 64B per row-chunk per step
  int p0 = 0, p1 = BUF3, p2 = 2 * BUF3;
  STAGE3(p0, 0)
  STAGE3(p1, 64)
  int t = 0;
  for (; t + 2 < nt; ++t) {
    WB3_4
    STAGE3(p2, (t + 2) << 6)
    COMP3(p0)
    int tmp = p0;
    p0 = p1;
    p1 = p2;
    p2 = tmp;
  }
  WB3_4
  COMP3(p0)
  WB3_0
  COMP3(p1)

  _Float16* outH = (_Float16*)outp + (long)z * zsOut;
  const int rj = (lane >> 4) << 2;
  const long MSZq = (long)BB * SS * DD;
#pragma unroll
  for (int mi = 0; mi < 8; ++mi) {
#pragma unroll
    for (int ni = 0; ni < 4; ++ni) {
      const int col = n0 + wn + ni * 16 + r16;
#pragma unroll
      for (int j = 0; j < 4; ++j) {
        const int row = m0 + wm + mi * 16 + rj + j;
        float vv = acc[mi][ni][j];
        if (emode == 1) {  // fused qkv scatter; V written transposed
          vv += bias[col];
          int wsel = col >> 10, c = col & 1023;
          int b_ = row >> 9, s_ = row & 511;
          int hh = c >> 7, hd_ = c & 127;
          if (wsel < 2) {
            outH[wsel * MSZq + (((long)(b_ * HH + hh)) * SS + s_) * HDD + hd_] =
                (_Float16)vv;
          } else {  // V -> [B*H][HD][S]
            outH[2 * MSZq + (((long)(b_ * HH + hh)) * HDD + hd_) * SS + s_] =
                (_Float16)vv;
          }
        } else if (emode == 2) {  // scores: scale + key-pad mask
          int b_ = z >> 3;
          vv = (amask[b_ * SS + col] == 0) ? -10000.0f : vv * SCALEF;
          outH[(long)row * Ndim + col] = (_Float16)vv;
        } else if (emode == 5) {  // exact GELU(bias+acc), f16
          vv += bias[col];
          vv = 0.5f * vv * (1.0f + erff(vv * 0.70710678118654752f));
          outH[(long)row * Ndim + col] = (_Float16)vv;
        } else {  // 6: f16 split-K partial, no bias
          outH[(long)row * Ndim + col] = (_Float16)vv;
        }
      }
    }
  }
}

// out[row][c] = (res? res : 0) + bias + sum of 4 f16 partials   (N=1024)
__global__ __launch_bounds__(256) void reduce4_kernel(
    const _Float16* __restrict__ parts, const float* __restrict__ res,
    const float* __restrict__ bias, float* __restrict__ out, long zs) {
  const int row = blockIdx.x;
  const int c = threadIdx.x << 2;
  const long base = (long)row * DD + c;
  float4 a;
  a.x = bias[c];
  a.y = bias[c + 1];
  a.z = bias[c + 2];
  a.w = bias[c + 3];
  if (res) {
    const float4 r = *reinterpret_cast<const float4*>(&res[base]);
    a.x += r.x;
    a.y += r.y;
    a.z += r.z;
    a.w += r.w;
  }
#pragma unroll
  for (int p = 0; p < 4; ++p) {
    const f16x4 h = *reinterpret_cast<const f16x4*>(&parts[p * zs + base]);
    a.x += (float)h[0];
    a.y += (float)h[1];
    a.z += (float)h[2];
    a.w += (float)h[3];
  }
  *reinterpret_cast<float4*>(&out[base]) = a;
}

// ===========================================================================
// old 128x64 kernel (kept for PV: N=128)
// ===========================================================================
#define TSZ 24576

#define STAGE(P, K0)                                                        \
  {                                                                         \
    _Pragma("unroll") for (int i = 0; i < 4; ++i)                           \
        gload16((const char*)(Az + (long)sra[i] * Kdim + (K0)) + sca[i],    \
                (P) + i * 4096 + wid * 1024);                               \
    _Pragma("unroll") for (int i = 0; i < 2; ++i)                           \
        gload16((const char*)(Bz + (long)srb[i] * Kdim + (K0)) + scb[i],    \
                (P) + 16384 + i * 4096 + wid * 1024);                       \
  }

#define COMPUTE(P)                                                          \
  {                                                                         \
    _Pragma("unroll") for (int kk = 0; kk < 2; ++kk) {                      \
      f16x8 af[4], bf[2];                                                   \
      _Pragma("unroll") for (int mi = 0; mi < 4; ++mi) {                    \
        const int R = wm + mi * 16 + r16;                                   \
        af[mi] = *(const f16x8*)((P) + R * 128 +                            \
                                 ((kk * 64 + kqb) ^ ((R & 7) << 4)));       \
      }                                                                     \
      _Pragma("unroll") for (int ni = 0; ni < 2; ++ni) {                    \
        const int R = wn + ni * 16 + r16;                                   \
        bf[ni] = *(const f16x8*)((P) + 16384 + R * 128 +                    \
                                 ((kk * 64 + kqb) ^ ((R & 7) << 4)));       \
      }                                                                     \
      _Pragma("unroll") for (int mi = 0; mi < 4; ++mi)                      \
          _Pragma("unroll") for (int ni = 0; ni < 2; ++ni)                  \
              acc[mi][ni] = __builtin_amdgcn_mfma_f32_16x16x32_f16(         \
                  af[mi], bf[ni], acc[mi][ni], 0, 0, 0);                    \
    }                                                                       \
  }

#define WAITBAR6                                      \
  {                                                   \
    asm volatile("s_waitcnt vmcnt(6)" ::: "memory");  \
    __builtin_amdgcn_s_barrier();                     \
  }
#define WAITBAR0                                      \
  {                                                   \
    asm volatile("s_waitcnt vmcnt(0)" ::: "memory");  \
    __builtin_amdgcn_s_barrier();                     \
  }

// emode: 3 pv-scatter only (kept minimal)
__global__ __launch_bounds__(256) void gemm2_kernel(
    const _Float16* __restrict__ Ag, const _Float16* __restrict__ Bg,
    void* __restrict__ outp, int Mdim, int Ndim, int Kdim, long zsA, long zsB,
    long zsOut) {
  __shared__ char lds[3 * TSZ];
  const int tid = threadIdx.x;
  const int lane = tid & 63;
  const int wid = tid >> 6;
  const int z = blockIdx.z;
  const int m0 = blockIdx.y * 128;
  const int n0 = blockIdx.x * 64;
  const _Float16* Az = Ag + (long)z * zsA + (long)m0 * Kdim;
  const _Float16* Bz = Bg + (long)z * zsB + (long)n0 * Kdim;

  const int wm = (wid >> 1) * 64;
  const int wn = (wid & 1) * 32;
  const int r16 = lane & 15;
  const int kqb = (lane >> 4) * 16;

  f32x4 acc[4][2];
#pragma unroll
  for (int mi = 0; mi < 4; ++mi)
#pragma unroll
    for (int ni = 0; ni < 2; ++ni) acc[mi][ni] = (f32x4){0.f, 0.f, 0.f, 0.f};

  int sra[4], srb[2], sca[4], scb[2];
  {
    const int cbl = (tid * 16) & 127;
#pragma unroll
    for (int i = 0; i < 4; ++i) {
      int r = i * 32 + (tid >> 3);
      sra[i] = r;
      sca[i] = cbl ^ ((r & 7) << 4);
    }
#pragma unroll
    for (int i = 0; i < 2; ++i) {
      int r = i * 32 + (tid >> 3);
      srb[i] = r;
      scb[i] = cbl ^ ((r & 7) << 4);
    }
  }

  const int nt = Kdim >> 6;
  char* p0 = lds;
  char* p1 = lds + TSZ;
  char* p2 = lds + 2 * TSZ;
  STAGE(p0, 0)
  STAGE(p1, 64)
  int t = 0;
  for (; t + 2 < nt; ++t) {
    WAITBAR6
    STAGE(p2, (t + 2) << 6)
    COMPUTE(p0)
    char* tmp = p0;
    p0 = p1;
    p1 = p2;
    p2 = tmp;
  }
  WAITBAR6
  COMPUTE(p0)
  WAITBAR0
  COMPUTE(p1)

  _Float16* outH = (_Float16*)outp;
  const int rj = (lane >> 4) << 2;
#pragma unroll
  for (int mi = 0; mi < 4; ++mi) {
#pragma unroll
    for (int ni = 0; ni < 2; ++ni) {
      const int col = n0 + wn + ni * 16 + r16;
#pragma unroll
      for (int j = 0; j < 4; ++j) {
        const int row = m0 + wm + mi * 16 + rj + j;
        const int b_ = z >> 3, hh = z & 7;
        outH[((long)(b_ * SS + row)) * DD + hh * HDD + col] =
            (_Float16)acc[mi][ni][j];
      }
    }
  }
}

// ---------------------------------------------------------------------------
__global__ __launch_bounds__(256) void embed_kernel(
    const int* __restrict__ ids, const int* __restrict__ curpos,
    const float* __restrict__ tok, const float* __restrict__ pos,
    float* __restrict__ h) {
  const int rs = blockIdx.x;
  const int s_ = rs & (SS - 1);
  const int t = ids[rs];
  const int p = curpos[0] + s_;
  const int c = threadIdx.x << 2;
  const float4 tv = *reinterpret_cast<const float4*>(&tok[(long)t * DD + c]);
  const float4 pv = *reinterpret_cast<const float4*>(&pos[(long)p * DD + c]);
  float4 o = {tv.x + pv.x, tv.y + pv.y, tv.z + pv.z, tv.w + pv.w};
  *reinterpret_cast<float4*>(&h[(long)rs * DD + c]) = o;
}

// LN: f32 in -> f16 out
__global__ __launch_bounds__(256) void ln_kernel(const float* __restrict__ in,
                                                 const float* __restrict__ g,
                                                 const float* __restrict__ bb,
                                                 _Float16* __restrict__ out) {
  const int row = blockIdx.x;
  const int c = threadIdx.x << 2;
  const float4 xv = *reinterpret_cast<const float4*>(&in[(long)row * DD + c]);
  float s = xv.x + xv.y + xv.z + xv.w;
  float ss = xv.x * xv.x + xv.y * xv.y + xv.z * xv.z + xv.w * xv.w;
#pragma unroll
  for (int off = 32; off; off >>= 1) {
    s += __shfl_down(s, off);
    ss += __shfl_down(ss, off);
  }
  __shared__ float red[8];
  const int wid = threadIdx.x >> 6, lane = threadIdx.x & 63;
  if (lane == 0) {
    red[wid] = s;
    red[4 + wid] = ss;
  }
  __syncthreads();
  if (threadIdx.x == 0) {
    s = red[0] + red[1] + red[2] + red[3];
    ss = red[4] + red[5] + red[6] + red[7];
    float mean = s * (1.0f / DD);
    float var = ss * (1.0f / DD) - mean * mean;
    red[0] = mean;
    red[1] = rsqrtf(var + EPSF);
  }
  __syncthreads();
  const float mean = red[0], rstd = red[1];
  const float4 gv = *reinterpret_cast<const float4*>(&g[c]);
  const float4 bv = *reinterpret_cast<const float4*>(&bb[c]);
  f16x4 o;
  o[0] = (_Float16)((xv.x - mean) * rstd * gv.x + bv.x);
  o[1] = (_Float16)((xv.y - mean) * rstd * gv.y + bv.y);
  o[2] = (_Float16)((xv.z - mean) * rstd * gv.z + bv.z);
  o[3] = (_Float16)((xv.w - mean) * rstd * gv.w + bv.w);
  *reinterpret_cast<f16x4*>(&out[(long)row * DD + c]) = o;
}

// wave-per-row softmax over 512 f16 cols, in place
__global__ __launch_bounds__(256) void softmax_kernel(_Float16* __restrict__ p) {
  const long row = (long)blockIdx.x * 4 + (threadIdx.x >> 6);
  const int lane = threadIdx.x & 63;
  _Float16* pr = p + row * SS;
  f16x8 hv = *reinterpret_cast<const f16x8*>(&pr[lane * 8]);
  float v[8];
#pragma unroll
  for (int j = 0; j < 8; ++j) v[j] = (float)hv[j];
  float m = v[0];
#pragma unroll
  for (int j = 1; j < 8; ++j) m = fmaxf(m, v[j]);
#pragma unroll
  for (int off = 1; off < 64; off <<= 1) m = fmaxf(m, __shfl_xor(m, off));
  float sum = 0.f;
#pragma unroll
  for (int j = 0; j < 8; ++j) {
    v[j] = expf(v[j] - m);
    sum += v[j];
  }
#pragma unroll
  for (int off = 1; off < 64; off <<= 1) sum += __shfl_xor(sum, off);
  const float inv = 1.0f / sum;
#pragma unroll
  for (int j = 0; j < 8; ++j) hv[j] = (_Float16)(v[j] * inv);
  *reinterpret_cast<f16x8*>(&pr[lane * 8]) = hv;
}

// W [K][N] f32 -> WT [N][K] f16  (64x64 tiles via LDS)
__global__ __launch_bounds__(256) void wtrans_kernel(
    const float* __restrict__ W, _Float16* __restrict__ WT, int K, int N) {
  __shared__ float t[64][65];
  const int n0 = blockIdx.x * 64, k0 = blockIdx.y * 64;
  const int tx = threadIdx.x & 63;
  const int ty = threadIdx.x >> 6;
#pragma unroll
  for (int i = 0; i < 16; ++i)
    t[i * 4 + ty][tx] = W[(long)(k0 + i * 4 + ty) * N + n0 + tx];
  __syncthreads();
#pragma unroll
  for (int i = 0; i < 16; ++i) {
    const int r = i * 4 + ty;
    WT[(long)(n0 + r) * K + k0 + tx] = (_Float16)t[tx][r];
  }
}

// pack per-layer qkv biases: bqkv[l][3072]
__global__ __launch_bounds__(256) void packb_kernel(
    const float* __restrict__ bq, const float* __restrict__ bk,
    const float* __restrict__ bv, float* __restrict__ bqkv) {
  const int i = blockIdx.x * 256 + threadIdx.x;
  const int l = i / (3 * DD), j = i % (3 * DD);
  float v;
  if (j < DD) v = bq[l * DD + j];
  else if (j < 2 * DD) v = bk[l * DD + j - DD];
  else v = bv[l * DD + j - 2 * DD];
  bqkv[i] = v;
}

// ---------------------------------------------------------------------------
extern "C" void kernel_launch(void* const* d_in, const int* in_sizes, int n_in,
                              void* d_out, int out_size, void* d_ws,
                              size_t ws_size, hipStream_t stream) {
  const int* ids = (const int*)d_in[0];
  const int* amask = (const int*)d_in[1];
  const int* curp = (const int*)d_in[2];
  const float* tok = (const float*)d_in[3];
  const float* pose = (const float*)d_in[4];
  const float* ln1s = (const float*)d_in[5];
  const float* ln1b = (const float*)d_in[6];
  const float* Wq = (const float*)d_in[7];
  const float* bq = (const float*)d_in[8];
  const float* Wk = (const float*)d_in[9];
  const float* bk = (const float*)d_in[10];
  const float* Wv = (const float*)d_in[11];
  const float* bv = (const float*)d_in[12];
  const float* Wo = (const float*)d_in[13];
  const float* bo = (const float*)d_in[14];
  const float* ln2s = (const float*)d_in[15];
  const float* ln2b = (const float*)d_in[16];
  const float* W1 = (const float*)d_in[17];
  const float* b1 = (const float*)d_in[18];
  const float* W2 = (const float*)d_in[19];
  const float* b2 = (const float*)d_in[20];
  const float* lnfs = (const float*)d_in[21];
  const float* lnfb = (const float*)d_in[22];
  const float* Wout = (const float*)d_in[23];
  const float* bout = (const float*)d_in[24];

  const long MSZ = (long)BB * SS * DD;  // 4M elements
  char* wsp = (char*)d_ws;
  float* h = (float*)wsp;                              // 16MB f32
  _Float16* x = (_Float16*)(wsp + 16u * 1024 * 1024);  // 8MB
  _Float16* q = x + MSZ;    // 8MB  (q, k, vT contiguous: qkv scatter target)
  _Float16* kb = q + MSZ;   // 8MB
  _Float16* vt = kb + MSZ;  // 8MB  [B*H][HD][S]
  _Float16* big = vt + MSZ; // 32MB (scores/probs, MLP mid)
  _Float16* wqkvT = big + (long)BB * HH * SS * SS;  // 6MB [3072][1024]
  _Float16* woT = wqkvT + 3L * DD * DD;             // 2MB
  _Float16* w1T = woT + (long)DD * DD;              // 8MB
  _Float16* w2T = w1T + (long)DD * FFF;             // 8MB
  float* bqkv = (float*)(w2T + (long)FFF * DD);     // 72KB
  _Float16* parts = (_Float16*)(bqkv + LL * 3 * DD);  // 32MB (4x f16 partials)

  const int M = BB * SS;  // 4096
  dim3 blk(256);
  dim3 blk5(512);

  embed_kernel<<<M, blk, 0, stream>>>(ids, curp, tok, pose, h);
  packb_kernel<<<(LL * 3 * DD) / 256, blk, 0, stream>>>(bq, bk, bv, bqkv);

  const dim3 gQKV(3 * DD / 256, M / 256, 1);    // (12,16)
  const dim3 gS(SS / 256, SS / 256, BB * HH);   // (2,2,64)
  const dim3 gV(HDD / 64, SS / 128, BB * HH);   // (2,4,64) old kernel
  const dim3 gF1(FFF / 256, M / 256, 1);        // (16,16)
  const dim3 gKS(DD / 256, M / 256, 4);         // (4,16,4) split-K N=1024
  const dim3 gWt(DD / 64, DD / 64);
  const dim3 gW1t(FFF / 64, DD / 64);
  const dim3 gW2t(DD / 64, FFF / 64);
  const long pzs = (long)M * DD;  // partial stride

  for (int l = 0; l < LL; ++l) {
    wtrans_kernel<<<gWt, blk, 0, stream>>>(Wq + (long)l * DD * DD, wqkvT, DD, DD);
    wtrans_kernel<<<gWt, blk, 0, stream>>>(Wk + (long)l * DD * DD,
                                           wqkvT + (long)DD * DD, DD, DD);
    wtrans_kernel<<<gWt, blk, 0, stream>>>(Wv + (long)l * DD * DD,
                                           wqkvT + 2L * DD * DD, DD, DD);
    wtrans_kernel<<<gWt, blk, 0, stream>>>(Wo + (long)l * DD * DD, woT, DD, DD);
    wtrans_kernel<<<gW1t, blk, 0, stream>>>(W1 + (long)l * DD * FFF, w1T, DD, FFF);
    wtrans_kernel<<<gW2t, blk, 0, stream>>>(W2 + (long)l * FFF * DD, w2T, FFF, DD);

    ln_kernel<<<M, blk, 0, stream>>>(h, ln1s + l * DD, ln1b + l * DD, x);
    // QKV: [4096,3072,1024]
    gemm3_kernel<<<gQKV, blk5, 0, stream>>>(x, wqkvT, bqkv + l * 3 * DD, q,
                                            nullptr, M, 3 * DD, DD, DD, 0, 0,
                                            0, 1);
    // scores: z=64 of [512,512,128]
    gemm3_kernel<<<gS, blk5, 0, stream>>>(q, kb, nullptr, big, amask, SS, SS,
                                          HDD, HDD, (long)SS * HDD,
                                          (long)SS * HDD, (long)SS * SS, 2);
    softmax_kernel<<<(BB * HH * SS) / 4, blk, 0, stream>>>(big);
    // PV: old kernel, z=64 of [512,128,512]
    gemm2_kernel<<<gV, blk, 0, stream>>>(big, vt, x, SS, HDD, SS,
                                         (long)SS * SS, (long)SS * HDD, 0);
    // Wo: split-K4 [4096,1024,1024] -> partials, then reduce(+h residual)
    gemm3_kernel<<<gKS, blk5, 0, stream>>>(x, woT, nullptr, parts, nullptr, M,
                                           DD, DD / 4, DD, DD / 4, DD / 4, pzs,
                                           6);
    reduce4_kernel<<<M, blk, 0, stream>>>(parts, h, bo + l * DD, h, pzs);
    ln_kernel<<<M, blk, 0, stream>>>(h, ln2s + l * DD, ln2b + l * DD, x);
    // MLP up + GELU: [4096,4096,1024]
    gemm3_kernel<<<gF1, blk5, 0, stream>>>(x, w1T, b1 + l * FFF, big, nullptr,
                                           M, FFF, DD, DD, 0, 0, 0, 5);
    // MLP down: split-K4 [4096,1024,4096] -> partials, reduce(+h residual)
    gemm3_kernel<<<gKS, blk5, 0, stream>>>(big, w2T, nullptr, parts, nullptr,
                                           M, DD, FFF / 4, FFF, FFF / 4,
                                           FFF / 4, pzs, 6);
    reduce4_kernel<<<M, blk, 0, stream>>>(parts, h, b2 + l * DD, h, pzs);
  }
  ln_kernel<<<M, blk, 0, stream>>>(h, lnfs, lnfb, x);
  wtrans_kernel<<<gWt, blk, 0, stream>>>(Wout, wqkvT, DD, DD);
  // final: split-K4 [4096,1024,1024] -> partials, reduce(bias only) -> d_out
  gemm3_kernel<<<gKS, blk5, 0, stream>>>(x, wqkvT, nullptr, parts, nullptr, M,
                                         DD, DD / 4, DD, DD / 4, DD / 4, pzs,
                                         6);
  reduce4_kernel<<<M, blk, 0, stream>>>(parts, nullptr, bout, (float*)d_out,
                                        pzs);
}